// Round 5
// baseline (130.427 us; speedup 1.0000x reference)
//
#include <hip/hip_runtime.h>

#define NTOK 256
#define LOG2E 1.44269504088896340736f
#define LN_EPS 1e-5f

// Grid: 1024 blocks (one per batch row) x 512 threads.
// Thread t: qpair = t>>2 -> owns queries {qpair, qpair+128};
//           kq    = t&3  -> owns key quarter [kq*64, kq*64+64).
// Split-k partials combined via __shfl_xor within each 4-lane quad (no LDS,
// no barrier). Single __syncthreads after KV staging. 8 waves/SIMD.
__global__ __launch_bounds__(512, 8)
void att_decoder_kernel(
    const float* __restrict__ x, const float* __restrict__ m,
    const float* __restrict__ sa_w_in, const float* __restrict__ sa_b_in,
    const float* __restrict__ sa_w_out, const float* __restrict__ sa_b_out,
    const float* __restrict__ ca_w_in, const float* __restrict__ ca_b_in,
    const float* __restrict__ ca_w_out, const float* __restrict__ ca_b_out,
    const float* __restrict__ ln1_g, const float* __restrict__ ln1_b,
    const float* __restrict__ ln2_g, const float* __restrict__ ln2_b,
    const float* __restrict__ ln3_g, const float* __restrict__ ln3_b,
    const float* __restrict__ f_w1, const float* __restrict__ f_b1,
    const float* __restrict__ f_ln_g, const float* __restrict__ f_ln_b,
    const float* __restrict__ f_w2, const float* __restrict__ f_b2,
    float* __restrict__ out)
{
    const int tid   = threadIdx.x;
    const int row   = blockIdx.x;
    const int qpair = tid >> 2;          // 0..127
    const int kq    = tid & 3;           // key quarter

    // permuted KV: key j -> slot (j&63)*4 + (j>>6); iter i of quarter kq
    // reads slot i*4+kq -> 4 distinct addresses per wave in disjoint bank
    // quads (conflict-free broadcast).
    __shared__ float4 kv_sa[NTOK];       // 4 KB
    __shared__ float4 kv_ca[NTOK];       // 4 KB

    const float2* __restrict__ x2 = (const float2*)x;
    const float2* __restrict__ m2 = (const float2*)m;

    // ---- stage KV: threads 0-255 -> SA (from LN1(x)), 256-511 -> CA (from m)
    {
        const int j    = tid & 255;
        const int slot = ((j & 63) << 2) + (j >> 6);
        if (tid < 256) {
            float2 xv = x2[row * NTOK + j];
            float d = 0.5f * (xv.x - xv.y);
            float n = d * rsqrtf(d * d + LN_EPS);
            float h0 =  n * ln1_g[0] + ln1_b[0];
            float h1 = -n * ln1_g[1] + ln1_b[1];
            float4 kv;
            kv.x = h0*sa_w_in[4]  + h1*sa_w_in[5]  + sa_b_in[2];
            kv.y = h0*sa_w_in[6]  + h1*sa_w_in[7]  + sa_b_in[3];
            kv.z = h0*sa_w_in[8]  + h1*sa_w_in[9]  + sa_b_in[4];
            kv.w = h0*sa_w_in[10] + h1*sa_w_in[11] + sa_b_in[5];
            kv_sa[slot] = kv;
        } else {
            float2 mv = m2[row * NTOK + j];
            float4 kv;
            kv.x = mv.x*ca_w_in[4]  + mv.y*ca_w_in[5]  + ca_b_in[2];
            kv.y = mv.x*ca_w_in[6]  + mv.y*ca_w_in[7]  + ca_b_in[3];
            kv.z = mv.x*ca_w_in[8]  + mv.y*ca_w_in[9]  + ca_b_in[4];
            kv.w = mv.x*ca_w_in[10] + mv.y*ca_w_in[11] + ca_b_in[5];
            kv_ca[slot] = kv;
        }
    }

    // ---- own 2 tokens, LN1 ----
    float2 xa = x2[row * NTOK + qpair];
    float2 xb = x2[row * NTOK + qpair + 128];
    float h0a, h1a, h0b, h1b;
    {
        float da = 0.5f * (xa.x - xa.y);
        float na = da * rsqrtf(da * da + LN_EPS);
        h0a =  na * ln1_g[0] + ln1_b[0];
        h1a = -na * ln1_g[1] + ln1_b[1];
        float db = 0.5f * (xb.x - xb.y);
        float nb = db * rsqrtf(db * db + LN_EPS);
        h0b =  nb * ln1_g[0] + ln1_b[0];
        h1b = -nb * ln1_g[1] + ln1_b[1];
    }

    __syncthreads();   // the only barrier

    const float sc = 0.7071067811865476f * LOG2E;

    // ---- self-attention (64-key quarter, 2 queries share each KV read) ----
    {
        float qe0a = (h0a*sa_w_in[0] + h1a*sa_w_in[1] + sa_b_in[0]) * sc;
        float qe1a = (h0a*sa_w_in[2] + h1a*sa_w_in[3] + sa_b_in[1]) * sc;
        float qe0b = (h0b*sa_w_in[0] + h1b*sa_w_in[1] + sa_b_in[0]) * sc;
        float qe1b = (h0b*sa_w_in[2] + h1b*sa_w_in[3] + sa_b_in[1]) * sc;
        float la = 0.f, a0a = 0.f, a1a = 0.f;
        float lb = 0.f, a0b = 0.f, a1b = 0.f;
        #pragma unroll 8
        for (int i = 0; i < 64; ++i) {
            float4 kv = kv_sa[(i << 2) + kq];
            float pa = __builtin_amdgcn_exp2f(qe0a * kv.x + qe1a * kv.y);
            float pb = __builtin_amdgcn_exp2f(qe0b * kv.x + qe1b * kv.y);
            la += pa; a0a += pa * kv.z; a1a += pa * kv.w;
            lb += pb; a0b += pb * kv.z; a1b += pb * kv.w;
        }
        // quad butterfly: sum the 4 key-quarters (lanes differ only in kq)
        la  += __shfl_xor(la, 1);  la  += __shfl_xor(la, 2);
        a0a += __shfl_xor(a0a, 1); a0a += __shfl_xor(a0a, 2);
        a1a += __shfl_xor(a1a, 1); a1a += __shfl_xor(a1a, 2);
        lb  += __shfl_xor(lb, 1);  lb  += __shfl_xor(lb, 2);
        a0b += __shfl_xor(a0b, 1); a0b += __shfl_xor(a0b, 2);
        a1b += __shfl_xor(a1b, 1); a1b += __shfl_xor(a1b, 2);
        float ra = 1.0f / la, rb = 1.0f / lb;
        a0a *= ra; a1a *= ra; a0b *= rb; a1b *= rb;
        h0a += a0a*sa_w_out[0] + a1a*sa_w_out[1] + sa_b_out[0];
        h1a += a0a*sa_w_out[2] + a1a*sa_w_out[3] + sa_b_out[1];
        h0b += a0b*sa_w_out[0] + a1b*sa_w_out[1] + sa_b_out[0];
        h1b += a0b*sa_w_out[2] + a1b*sa_w_out[3] + sa_b_out[1];
    }

    // ---- LN2 ----
    {
        float da = 0.5f * (h0a - h1a);
        float na = da * rsqrtf(da * da + LN_EPS);
        h0a =  na * ln2_g[0] + ln2_b[0];
        h1a = -na * ln2_g[1] + ln2_b[1];
        float db = 0.5f * (h0b - h1b);
        float nb = db * rsqrtf(db * db + LN_EPS);
        h0b =  nb * ln2_g[0] + ln2_b[0];
        h1b = -nb * ln2_g[1] + ln2_b[1];
    }

    // ---- cross-attention ----
    {
        float qe0a = (h0a*ca_w_in[0] + h1a*ca_w_in[1] + ca_b_in[0]) * sc;
        float qe1a = (h0a*ca_w_in[2] + h1a*ca_w_in[3] + ca_b_in[1]) * sc;
        float qe0b = (h0b*ca_w_in[0] + h1b*ca_w_in[1] + ca_b_in[0]) * sc;
        float qe1b = (h0b*ca_w_in[2] + h1b*ca_w_in[3] + ca_b_in[1]) * sc;
        float la = 0.f, a0a = 0.f, a1a = 0.f;
        float lb = 0.f, a0b = 0.f, a1b = 0.f;
        #pragma unroll 8
        for (int i = 0; i < 64; ++i) {
            float4 kv = kv_ca[(i << 2) + kq];
            float pa = __builtin_amdgcn_exp2f(qe0a * kv.x + qe1a * kv.y);
            float pb = __builtin_amdgcn_exp2f(qe0b * kv.x + qe1b * kv.y);
            la += pa; a0a += pa * kv.z; a1a += pa * kv.w;
            lb += pb; a0b += pb * kv.z; a1b += pb * kv.w;
        }
        la  += __shfl_xor(la, 1);  la  += __shfl_xor(la, 2);
        a0a += __shfl_xor(a0a, 1); a0a += __shfl_xor(a0a, 2);
        a1a += __shfl_xor(a1a, 1); a1a += __shfl_xor(a1a, 2);
        lb  += __shfl_xor(lb, 1);  lb  += __shfl_xor(lb, 2);
        a0b += __shfl_xor(a0b, 1); a0b += __shfl_xor(a0b, 2);
        a1b += __shfl_xor(a1b, 1); a1b += __shfl_xor(a1b, 2);
        float ra = 1.0f / la, rb = 1.0f / lb;
        a0a *= ra; a1a *= ra; a0b *= rb; a1b *= rb;
        h0a += a0a*ca_w_out[0] + a1a*ca_w_out[1] + ca_b_out[0];
        h1a += a0a*ca_w_out[2] + a1a*ca_w_out[3] + ca_b_out[1];
        h0b += a0b*ca_w_out[0] + a1b*ca_w_out[1] + ca_b_out[0];
        h1b += a0b*ca_w_out[2] + a1b*ca_w_out[3] + ca_b_out[1];
    }

    if (kq != 0) return;   // quad lanes 1-3 are redundant from here

    // ---- LN3 ----
    {
        float da = 0.5f * (h0a - h1a);
        float na = da * rsqrtf(da * da + LN_EPS);
        h0a =  na * ln3_g[0] + ln3_b[0];
        h1a = -na * ln3_g[1] + ln3_b[1];
        float db = 0.5f * (h0b - h1b);
        float nb = db * rsqrtf(db * db + LN_EPS);
        h0b =  nb * ln3_g[0] + ln3_b[0];
        h1b = -nb * ln3_g[1] + ln3_b[1];
    }

    // ---- FFN: Linear(2,10)->LN(10)->ReLU->Linear(10,2), residual ----
    #pragma unroll
    for (int tok = 0; tok < 2; ++tok) {
        float h0 = tok ? h0b : h0a;
        float h1 = tok ? h1b : h1a;
        float ff[10];
        #pragma unroll
        for (int i = 0; i < 10; ++i)
            ff[i] = h0*f_w1[2*i] + h1*f_w1[2*i+1] + f_b1[i];
        float mu = 0.f;
        #pragma unroll
        for (int i = 0; i < 10; ++i) mu += ff[i];
        mu *= 0.1f;
        float var = 0.f;
        #pragma unroll
        for (int i = 0; i < 10; ++i) { float d = ff[i] - mu; var += d * d; }
        var *= 0.1f;
        float r = rsqrtf(var + LN_EPS);
        float o0 = 0.f, o1 = 0.f;
        #pragma unroll
        for (int i = 0; i < 10; ++i) {
            float n = (ff[i] - mu) * r * f_ln_g[i] + f_ln_b[i];
            n = fmaxf(n, 0.f);
            o0 += n * f_w2[i];               // f_w2 is [2,10] row-major
            o1 += n * f_w2[10 + i];
        }
        if (tok) { h0b = h0 + o0 + f_b2[0]; h1b = h1 + o1 + f_b2[1]; }
        else     { h0a = h0 + o0 + f_b2[0]; h1a = h1 + o1 + f_b2[1]; }
    }

    float2* out2 = (float2*)out;
    out2[row * NTOK + qpair]       = make_float2(h0a, h1a);
    out2[row * NTOK + qpair + 128] = make_float2(h0b, h1b);
}

extern "C" void kernel_launch(void* const* d_in, const int* in_sizes, int n_in,
                              void* d_out, int out_size, void* d_ws, size_t ws_size,
                              hipStream_t stream) {
    const float* x        = (const float*)d_in[0];
    const float* m        = (const float*)d_in[1];
    const float* sa_w_in  = (const float*)d_in[2];
    const float* sa_b_in  = (const float*)d_in[3];
    const float* sa_w_out = (const float*)d_in[4];
    const float* sa_b_out = (const float*)d_in[5];
    const float* ca_w_in  = (const float*)d_in[6];
    const float* ca_b_in  = (const float*)d_in[7];
    const float* ca_w_out = (const float*)d_in[8];
    const float* ca_b_out = (const float*)d_in[9];
    const float* ln1_g    = (const float*)d_in[10];
    const float* ln1_b    = (const float*)d_in[11];
    const float* ln2_g    = (const float*)d_in[12];
    const float* ln2_b    = (const float*)d_in[13];
    const float* ln3_g    = (const float*)d_in[14];
    const float* ln3_b    = (const float*)d_in[15];
    const float* f_w1     = (const float*)d_in[16];
    const float* f_b1     = (const float*)d_in[17];
    const float* f_ln_g   = (const float*)d_in[18];
    const float* f_ln_b   = (const float*)d_in[19];
    const float* f_w2     = (const float*)d_in[20];
    const float* f_b2     = (const float*)d_in[21];

    const int nbatch = in_sizes[0] / (NTOK * 2);   // 1024
    att_decoder_kernel<<<nbatch, 512, 0, stream>>>(
        x, m, sa_w_in, sa_b_in, sa_w_out, sa_b_out,
        ca_w_in, ca_b_in, ca_w_out, ca_b_out,
        ln1_g, ln1_b, ln2_g, ln2_b, ln3_g, ln3_b,
        f_w1, f_b1, f_ln_g, f_ln_b, f_w2, f_b2,
        (float*)d_out);
}